// Round 1
// baseline (649.344 us; speedup 1.0000x reference)
//
#include <hip/hip_runtime.h>
#include <hip/hip_bf16.h>

#define Bn 32
#define Sn 16
#define Tn 260
#define Dn 768
#define Pn 256
#define V4 (Dn/4)            // 192 float4 per row
#define THRESHOLD_F 0.5f
#define MIN_KEEP 4

// d_out flat layout (all float32):
//   [0, 102236160)                 sparse_tokens (B,S,T,D)
//   [102236160, +B*T)              particle_pad_mask (B,260)
//   [102244480, +B*P)              padded_idx (B,256)
//   [102252672, +B*P)              valid (B,256)
//   [102260864]                    active_mean
#define OFF_MASK  102236160LL
#define OFF_PIDX  102244480LL
#define OFF_VALID 102252672LL
#define OFF_MEAN  102260864LL

// Kernel 1: one block per batch row. Computes scores = max_S z, active mask,
// stable partition (active indices ascending, then inactive ascending),
// fallback top-4 when no actives. Writes gather idx to ws + small outputs.
__global__ __launch_bounds__(Pn) void select_kernel(
    const float* __restrict__ z,   // (B,S,P)
    float* __restrict__ out,
    int* __restrict__ widx,        // ws: (B,P)
    int* __restrict__ wcounts)     // ws: (B)
{
    const int b = blockIdx.x;
    const int p = threadIdx.x;     // 256 threads

    // max over S (stride P between s slices -> coalesced across p)
    const float* zb = z + (long long)b * Sn * Pn + p;
    float sc = zb[0];
#pragma unroll
    for (int s = 1; s < Sn; ++s) sc = fmaxf(sc, zb[s * Pn]);

    __shared__ float ssc[Pn];
    __shared__ int   act[Pn];
    __shared__ int   order[Pn];
    ssc[p] = sc;
    int a = (sc > THRESHOLD_F) ? 1 : 0;
    act[p] = a;
    __syncthreads();

    // total active (uniform across threads)
    int total = 0;
    for (int i = 0; i < Pn; ++i) total += act[i];

    if (total == 0) {              // fallback: top-MIN_KEEP, ties -> lower index
        __syncthreads();           // everyone done reading act
        if (p == 0) {
            for (int k = 0; k < MIN_KEEP; ++k) {
                int best = -1; float bv = -3.0e38f;
                for (int i = 0; i < Pn; ++i) {
                    if (act[i]) continue;
                    if (ssc[i] > bv) { bv = ssc[i]; best = i; }
                }
                act[best] = 1;
            }
        }
        __syncthreads();
        a = act[p];
        total = MIN_KEEP;
    }

    // stable partition rank: actives keep index order first, then inactives
    int rankA = 0;
    for (int i = 0; i < p; ++i) rankA += act[i];
    int rank = a ? rankA : (total + (p - rankA));
    order[rank] = p;
    __syncthreads();

    int pidx = (p < total) ? order[p] : 0;
    widx[b * Pn + p] = pidx;

    float v = (p < total) ? 1.0f : 0.0f;
    out[OFF_PIDX  + (long long)b * Pn + p] = (float)pidx;
    out[OFF_VALID + (long long)b * Pn + p] = v;
    out[OFF_MASK  + (long long)b * Tn + p] = v;
    if (p < Tn - Pn) out[OFF_MASK + (long long)b * Tn + Pn + p] = 1.0f;
    if (p == 0) wcounts[b] = total;
}

// Kernel 2: active_mean = mean(counts)
__global__ void mean_kernel(const int* __restrict__ wcounts, float* __restrict__ out)
{
    int t = threadIdx.x;                       // 64 threads, 1 wave
    float v = (t < Bn) ? (float)wcounts[t] : 0.0f;
#pragma unroll
    for (int off = 32; off > 0; off >>= 1) v += __shfl_down(v, off);
    if (t == 0) out[OFF_MEAN] = v / (float)Bn;
}

// Kernel 3: the heavy gather. One block per (b,s,j) row, 192 lanes of float4.
// No integer division; widx read is wave-uniform (L1 broadcast).
__global__ __launch_bounds__(V4) void gather_kernel(
    const float4* __restrict__ tok,
    const int* __restrict__ widx,
    float4* __restrict__ out)
{
    const int j = blockIdx.x;      // 0..259
    const int s = blockIdx.y;      // 0..15
    const int b = blockIdx.z;      // 0..31
    const int lane = threadIdx.x;  // 0..191

    const int idx = (j < Pn) ? widx[b * Pn + j] : j;
    const long long bs = (long long)b * Sn + s;
    out[(bs * Tn + j) * V4 + lane] = tok[(bs * Tn + idx) * V4 + lane];
}

extern "C" void kernel_launch(void* const* d_in, const int* in_sizes, int n_in,
                              void* d_out, int out_size, void* d_ws, size_t ws_size,
                              hipStream_t stream) {
    const float* tokens = (const float*)d_in[0];   // (32,16,260,768) f32
    const float* z      = (const float*)d_in[1];   // (32,16,256)     f32
    float* out = (float*)d_out;

    int* widx    = (int*)d_ws;                     // B*P ints
    int* wcounts = widx + Bn * Pn;                 // B ints

    select_kernel<<<dim3(Bn), dim3(Pn), 0, stream>>>(z, out, widx, wcounts);
    mean_kernel<<<dim3(1), dim3(64), 0, stream>>>(wcounts, out);
    gather_kernel<<<dim3(Tn, Sn, Bn), dim3(V4), 0, stream>>>(
        (const float4*)tokens, widx, (float4*)out);
}